// Round 1
// baseline (1974.965 us; speedup 1.0000x reference)
//
#include <hip/hip_runtime.h>
#include <hip/hip_bf16.h>
#include <math.h>

#define HEADS   6
#define DMODEL  1024
#define NPROJ   384
#define DSP     64
#define NPOOL   2048
#define NROWS   8192
#define TILE_M  64
#define CHUNK   128
#define NCHUNKS 16
#define KEEP    16

__device__ __forceinline__ bool bet_f(float v, int vi, float w, int wi) {
    return (v > w) || (v == w && vi < wi);
}
__device__ __forceinline__ bool bet_d(double v, int vi, double w, int wi) {
    return (v > w) || (v == w && vi < wi);
}

// One block = one (head, 64-row tile). Does proj (fp64), logits (fp32),
// online softmax + top-8 prefilter, fp64 rescore of top-16, output write.
__global__ __launch_bounds__(256)
void router_all(const float* __restrict__ x, const float* __restrict__ Wm,
                const float* __restrict__ bb, const float* __restrict__ emb,
                float* __restrict__ out)
{
    __shared__ __align__(16) float          h_hi[64*68];   // [k][row]
    __shared__ __align__(16) __hip_bfloat16 h_lo[64*68];   // [k][row] low part
    __shared__ __align__(16) double         stage_d[4224]; // 33792 B, multi-use
    float* stage = reinterpret_cast<float*>(stage_d);

    const int t    = threadIdx.x;
    const int cg   = t & 15;   // col group
    const int rg   = t >> 4;   // row group
    const int head = blockIdx.y;
    const int row0 = blockIdx.x * TILE_M;

    // ================= Phase 0: fp64 proj tile =================
    {
        double* x_t = stage_d;           // [32][66]  (k-major, padded)
        double* w_t = stage_d + 32*66;   // [32][66]
        double acc0[4][4];
        #pragma unroll
        for (int i=0;i<4;i++) {
            #pragma unroll
            for (int j=0;j<4;j++) acc0[i][j] = 0.0;
        }

        const int xr   = t >> 3;        // 0..31
        const int xseg = (t & 7) * 4;   // k offset

        for (int kk = 0; kk < DMODEL; kk += 32) {
            const float4 xv0 = *(const float4*)(x + (size_t)(row0+xr   )*DMODEL + kk + xseg);
            const float4 xv1 = *(const float4*)(x + (size_t)(row0+xr+32)*DMODEL + kk + xseg);
            const int wr0 = t >> 4, wc0 = (t & 15) * 4;
            const int wr1 = wr0 + 16;
            const float4 wv0 = *(const float4*)(Wm + (size_t)(kk+wr0)*NPROJ + head*64 + wc0);
            const float4 wv1 = *(const float4*)(Wm + (size_t)(kk+wr1)*NPROJ + head*64 + wc0);
            __syncthreads();   // previous inner-loop reads of x_t/w_t done
            x_t[(xseg+0)*66 + xr]    = (double)xv0.x;
            x_t[(xseg+1)*66 + xr]    = (double)xv0.y;
            x_t[(xseg+2)*66 + xr]    = (double)xv0.z;
            x_t[(xseg+3)*66 + xr]    = (double)xv0.w;
            x_t[(xseg+0)*66 + xr+32] = (double)xv1.x;
            x_t[(xseg+1)*66 + xr+32] = (double)xv1.y;
            x_t[(xseg+2)*66 + xr+32] = (double)xv1.z;
            x_t[(xseg+3)*66 + xr+32] = (double)xv1.w;
            w_t[wr0*66 + wc0+0] = (double)wv0.x;
            w_t[wr0*66 + wc0+1] = (double)wv0.y;
            w_t[wr0*66 + wc0+2] = (double)wv0.z;
            w_t[wr0*66 + wc0+3] = (double)wv0.w;
            w_t[wr1*66 + wc0+0] = (double)wv1.x;
            w_t[wr1*66 + wc0+1] = (double)wv1.y;
            w_t[wr1*66 + wc0+2] = (double)wv1.z;
            w_t[wr1*66 + wc0+3] = (double)wv1.w;
            __syncthreads();
            #pragma unroll 4
            for (int k=0;k<32;k++) {
                const double2 a0 = *(const double2*)&x_t[k*66 + rg*4];
                const double2 a1 = *(const double2*)&x_t[k*66 + rg*4 + 2];
                const double2 b0 = *(const double2*)&w_t[k*66 + cg*4];
                const double2 b1 = *(const double2*)&w_t[k*66 + cg*4 + 2];
                double xs4[4] = {a0.x, a0.y, a1.x, a1.y};
                double ws4[4] = {b0.x, b0.y, b1.x, b1.y};
                #pragma unroll
                for (int i=0;i<4;i++) {
                    #pragma unroll
                    for (int j=0;j<4;j++)
                        acc0[i][j] = fma(xs4[i], ws4[j], acc0[i][j]);
                }
            }
        }
        __syncthreads();
        // bias + hi/lo split, store h planes [k][row]
        #pragma unroll
        for (int j=0;j<4;j++) {
            const double bj = (double)bb[head*64 + cg*4 + j];
            #pragma unroll
            for (int i=0;i<4;i++) {
                const double v  = acc0[i][j] + bj;
                const float  hi = (float)v;
                h_hi[(cg*4+j)*68 + rg*4 + i] = hi;
                h_lo[(cg*4+j)*68 + rg*4 + i] = __float2bfloat16((float)(v - (double)hi));
            }
        }
    }

    // ================= Phase 1: fp32 logits + online softmax + top-8 =================
    int psel = 0;                 // pools: [fqk,fqk,fv,rqk,rqk,rv] -> 0,0,1,2,2,3
    if (head >= 2) psel = 1;
    if (head >= 3) psel = 2;
    if (head >= 5) psel = 3;
    const float* epool = emb + (size_t)psel * NPOOL * DSP;

    float mrow[4], zrow[4], tv[4][8];
    int   ti[4][8];
    #pragma unroll
    for (int i=0;i<4;i++) {
        mrow[i] = -INFINITY; zrow[i] = 0.f;
        #pragma unroll
        for (int s=0;s<8;s++) { tv[i][s] = -INFINITY; ti[i][s] = 0x7fffffff; }
    }

    float* e_t = stage;               // [64][132]  normalized emb, k-major
    const int erow = t >> 1;          // 0..127
    const int eh   = (t & 1) * 32;    // half-row k offset

    for (int ch=0; ch<NCHUNKS; ++ch) {
        const float* esrc = epool + (size_t)(ch*CHUNK + erow)*DSP + eh;
        float4 f[8];
        #pragma unroll
        for (int q=0;q<8;q++) f[q] = *(const float4*)(esrc + q*4);
        float ss = 0.f;
        #pragma unroll
        for (int q=0;q<8;q++) ss += f[q].x*f[q].x + f[q].y*f[q].y + f[q].z*f[q].z + f[q].w*f[q].w;
        ss += __shfl_xor(ss, 1, 64);
        const float inv = 1.0f / fmaxf(sqrtf(ss), 1e-12f);
        __syncthreads();   // previous chunk's GEMM reads of e_t done
        #pragma unroll
        for (int q=0;q<8;q++) {
            e_t[(eh+q*4+0)*132 + erow] = f[q].x * inv;
            e_t[(eh+q*4+1)*132 + erow] = f[q].y * inv;
            e_t[(eh+q*4+2)*132 + erow] = f[q].z * inv;
            e_t[(eh+q*4+3)*132 + erow] = f[q].w * inv;
        }
        __syncthreads();

        float acc[4][8];
        #pragma unroll
        for (int i=0;i<4;i++) {
            #pragma unroll
            for (int j=0;j<8;j++) acc[i][j] = 0.f;
        }
        #pragma unroll 8
        for (int k=0;k<64;k++) {
            const float4 hv = *(const float4*)&h_hi[k*68 + rg*4];
            const float4 e0 = *(const float4*)&e_t[k*132 + cg*8];
            const float4 e1 = *(const float4*)&e_t[k*132 + cg*8 + 4];
            const float hva[4] = {hv.x, hv.y, hv.z, hv.w};
            const float ea[8]  = {e0.x, e0.y, e0.z, e0.w, e1.x, e1.y, e1.z, e1.w};
            #pragma unroll
            for (int i=0;i<4;i++) {
                #pragma unroll
                for (int j=0;j<8;j++)
                    acc[i][j] = fmaf(hva[i], ea[j], acc[i][j]);
            }
        }
        const int colbase = ch*CHUNK + cg*8;
        #pragma unroll
        for (int i=0;i<4;i++) {
            #pragma unroll
            for (int j=0;j<8;j++) {
                const float v = acc[i][j];
                const int   c = colbase + j;
                const float nm = fmaxf(mrow[i], v);
                zrow[i] = zrow[i]*__expf(mrow[i]-nm) + __expf(v-nm);
                mrow[i] = nm;
                if (bet_f(v, c, tv[i][7], ti[i][7])) {
                    tv[i][7] = v; ti[i][7] = c;
                    #pragma unroll
                    for (int s=7;s>0;--s) {
                        const bool sw = bet_f(tv[i][s],ti[i][s],tv[i][s-1],ti[i][s-1]);
                        const float a = tv[i][s]; const int b = ti[i][s];
                        tv[i][s]   = sw ? tv[i][s-1] : tv[i][s];
                        ti[i][s]   = sw ? ti[i][s-1] : ti[i][s];
                        tv[i][s-1] = sw ? a : tv[i][s-1];
                        ti[i][s-1] = sw ? b : ti[i][s-1];
                    }
                }
            }
        }
    }
    __syncthreads();   // all e_t reads done; stage is free

    // ================= Phase 2: merge per-row state across 16 col-threads =================
    float* mz   = stage;             // [64][34]  (m,Z) pairs
    float* cand = stage + 64*34;     // [64][66]  (val,idx) x 4 groups x 8
    #pragma unroll
    for (int i=0;i<4;i++) {
        mz[(rg*4+i)*34 + cg*2 + 0] = mrow[i];
        mz[(rg*4+i)*34 + cg*2 + 1] = zrow[i];
    }
    __syncthreads();

    float mg = -INFINITY, Zg = 0.f;
    float gv[KEEP]; int gi[KEEP];
    if (t < 64) {
        #pragma unroll
        for (int c=0;c<16;c++) mg = fmaxf(mg, mz[t*34 + c*2]);
        #pragma unroll
        for (int c=0;c<16;c++) Zg += mz[t*34 + c*2 + 1] * __expf(mz[t*34 + c*2] - mg);
        #pragma unroll
        for (int s=0;s<KEEP;s++) { gv[s] = -INFINITY; gi[s] = 0x7fffffff; }
    }
    for (int r=0;r<4;r++) {
        __syncthreads();
        if ((cg>>2) == r) {
            #pragma unroll
            for (int i=0;i<4;i++) {
                #pragma unroll
                for (int s=0;s<8;s++) {
                    cand[(rg*4+i)*66 + (cg&3)*16 + s*2    ] = tv[i][s];
                    cand[(rg*4+i)*66 + (cg&3)*16 + s*2 + 1] = __int_as_float(ti[i][s]);
                }
            }
        }
        __syncthreads();
        if (t < 64) {
            for (int g=0; g<4; ++g) {
                #pragma unroll
                for (int s=0;s<8;s++) {
                    const float v  = cand[t*66 + g*16 + s*2];
                    const int   ix = __float_as_int(cand[t*66 + g*16 + s*2 + 1]);
                    if (bet_f(v, ix, gv[KEEP-1], gi[KEEP-1])) {
                        gv[KEEP-1] = v; gi[KEEP-1] = ix;
                        #pragma unroll
                        for (int s2=KEEP-1; s2>0; --s2) {
                            const bool sw = bet_f(gv[s2],gi[s2],gv[s2-1],gi[s2-1]);
                            const float a = gv[s2]; const int b = gi[s2];
                            gv[s2]   = sw ? gv[s2-1] : gv[s2];
                            gi[s2]   = sw ? gi[s2-1] : gi[s2];
                            gv[s2-1] = sw ? a : gv[s2-1];
                            gi[s2-1] = sw ? b : gi[s2-1];
                        }
                    }
                }
            }
        }
    }
    __syncthreads();

    // ================= Phase 3: fp64 rescore of top-16 candidates =================
    int*    ridx = reinterpret_cast<int*>(stage_d);  // [64][17]
    double* rv   = stage_d + 544;                    // [64][17]
    if (t < 64) {
        #pragma unroll
        for (int s=0;s<KEEP;s++) ridx[t*17 + s] = gi[s];
    }
    __syncthreads();
    {
        const int row = t >> 2, q = t & 3;   // 4 candidates per thread
        int ixs[4];
        const float* ep[4];
        #pragma unroll
        for (int s=0;s<4;s++) {
            ixs[s] = ridx[row*17 + q*4 + s];
            ep[s]  = epool + (size_t)ixs[s]*DSP;
        }
        double nn[4] = {0,0,0,0}, dd[4] = {0,0,0,0};
        for (int k4=0; k4<64; k4+=4) {
            double h4[4];
            #pragma unroll
            for (int u=0;u<4;u++)
                h4[u] = (double)h_hi[(k4+u)*68 + row]
                      + (double)__bfloat162float(h_lo[(k4+u)*68 + row]);
            #pragma unroll
            for (int s=0;s<4;s++) {
                const float4 ev = *(const float4*)(ep[s] + k4);
                const double e0 = (double)ev.x, e1 = (double)ev.y;
                const double e2 = (double)ev.z, e3 = (double)ev.w;
                nn[s] += e0*e0 + e1*e1 + e2*e2 + e3*e3;
                dd[s] += h4[0]*e0 + h4[1]*e1 + h4[2]*e2 + h4[3]*e3;
            }
        }
        #pragma unroll
        for (int s=0;s<4;s++)
            rv[row*17 + q*4 + s] = dd[s] / fmax(sqrt(nn[s]), 1e-12);
    }
    __syncthreads();

    // ================= Phase 4: final fp64 top-8 select + output =================
    float ov[8]; int oi[8];
    if (t < 64) {
        double bv[8];
        #pragma unroll
        for (int s=0;s<8;s++) { bv[s] = -INFINITY; oi[s] = 0x7fffffff; }
        for (int s=0;s<KEEP;s++) {
            const double v  = rv[t*17 + s];
            const int    ix = ridx[t*17 + s];
            if (bet_d(v, ix, bv[7], oi[7])) {
                bv[7] = v; oi[7] = ix;
                #pragma unroll
                for (int s2=7; s2>0; --s2) {
                    const bool sw = bet_d(bv[s2],oi[s2],bv[s2-1],oi[s2-1]);
                    const double a = bv[s2]; const int b = oi[s2];
                    bv[s2]   = sw ? bv[s2-1] : bv[s2];
                    oi[s2]   = sw ? oi[s2-1] : oi[s2];
                    bv[s2-1] = sw ? a : bv[s2-1];
                    oi[s2-1] = sw ? b : oi[s2-1];
                }
            }
        }
        float denom = 1e-8f * Zg;
        #pragma unroll
        for (int s=0;s<8;s++) { ov[s] = __expf((float)(bv[s] - (double)mg)); denom += ov[s]; }
        const float rd = 1.0f / denom;
        #pragma unroll
        for (int s=0;s<8;s++) ov[s] *= rd;
    }

    // zero-fill this block's 64 output rows (512 KB), then scatter the 8 values/row
    const size_t obase = ((size_t)head*NROWS + row0) * 2048;
    const float4 z4 = make_float4(0.f, 0.f, 0.f, 0.f);
    for (int w=0; w<128; ++w) {
        *(float4*)(out + obase + (size_t)(w*256 + t)*4) = z4;
    }
    __syncthreads();   // drains vmcnt before barrier -> zero stores ordered before scatter
    if (t < 64) {
        float* orow = out + obase + (size_t)t*2048;
        #pragma unroll
        for (int s=0;s<8;s++) orow[oi[s]] = ov[s];
    }
}

extern "C" void kernel_launch(void* const* d_in, const int* in_sizes, int n_in,
                              void* d_out, int out_size, void* d_ws, size_t ws_size,
                              hipStream_t stream) {
    (void)in_sizes; (void)n_in; (void)d_ws; (void)ws_size; (void)out_size;
    const float* x   = (const float*)d_in[0];
    const float* Wm  = (const float*)d_in[1];
    const float* bb  = (const float*)d_in[2];
    const float* emb = (const float*)d_in[3];
    dim3 grid(NROWS / TILE_M, HEADS);
    router_all<<<grid, dim3(256), 0, stream>>>(x, Wm, bb, emb, (float*)d_out);
}

// Round 2
// 1504.426 us; speedup vs baseline: 1.3128x; 1.3128x over previous
//
#include <hip/hip_runtime.h>
#include <hip/hip_bf16.h>
#include <math.h>

#define HEADS   6
#define DMODEL  1024
#define NPROJ   384
#define DSP     64
#define NPOOL   2048
#define NROWS   8192
#define TILE_M  64
#define KT      64
#define CHUNK   64
#define NCHUNKS 32
#define KEEP    16

#define LOG2E_F 1.44269504088896340f
#define LOG2E_D 1.4426950408889634
#define C2      14.4269504088896340f   /* 10 * log2(e); logits provably < 10 */

__device__ __forceinline__ bool bet_f(float v, int vi, float w, int wi) {
    return (v > w) || (v == w && vi < wi);
}
__device__ __forceinline__ bool bet_d(double v, int vi, double w, int wi) {
    return (v > w) || (v == w && vi < wi);
}

// One block = one (head, 64-row tile).
// Phase 0: fp64 proj (x staged f32 in LDS, W streamed from global L1/L2).
// Phase 1: f32 logits (pre-scaled by log2e), fixed-ref exp2 Z, per-thread top-8.
// Phase 2: merge to per-row top-16.  Phase 3: fp64 rescore.  Phase 4: select+write.
__global__ __launch_bounds__(256, 3)
void router_all(const float* __restrict__ x, const float* __restrict__ Wm,
                const float* __restrict__ bb, const float* __restrict__ emb,
                float* __restrict__ out)
{
    __shared__ __align__(16) float          h_hi[64*68];   // [dspace][row]
    __shared__ __align__(16) __hip_bfloat16 h_lo[64*68];   // low 8 bits of h
    __shared__ __align__(16) float          stage[64*68];  // 17408 B, multi-use
    __shared__ float zbuf[64];
    // total LDS = 17408 + 8704 + 17408 + 256 = 43776 B -> 3 blocks/CU

    const int t    = threadIdx.x;
    const int cg   = t & 15;
    const int rg   = t >> 4;
    const int head = blockIdx.y;
    const int row0 = blockIdx.x * TILE_M;
    const size_t obase = ((size_t)head*NROWS + row0) * (size_t)NPOOL;

    // ================= Phase 0: fp64 proj =================
    {
        double acc0[4][4];
        #pragma unroll
        for (int i=0;i<4;i++) {
            #pragma unroll
            for (int j=0;j<4;j++) acc0[i][j] = 0.0;
        }
        const int xr = t >> 2;        // 0..63 row
        const int xq = t & 3;         // k quarter
        const float* wcol = Wm + head*64 + cg*4;

        for (int kk = 0; kk < DMODEL; kk += KT) {
            const float* xsrc = x + (size_t)(row0+xr)*DMODEL + kk + xq*16;
            float4 xv[4];
            #pragma unroll
            for (int q=0;q<4;q++) xv[q] = *(const float4*)(xsrc + q*4);
            __syncthreads();   // prev tile's stage reads done
            #pragma unroll
            for (int q=0;q<4;q++) {
                const int k = xq*16 + q*4;
                stage[(k+0)*68 + xr] = xv[q].x;
                stage[(k+1)*68 + xr] = xv[q].y;
                stage[(k+2)*68 + xr] = xv[q].z;
                stage[(k+3)*68 + xr] = xv[q].w;
            }
            __syncthreads();
            const float* wk = wcol + (size_t)kk*NPROJ;
            #pragma unroll 4
            for (int k=0;k<KT;k++) {
                const float4 xf = *(const float4*)&stage[k*68 + rg*4];
                const float4 wf = *(const float4*)(wk + (size_t)k*NPROJ);
                const double xd[4] = {(double)xf.x,(double)xf.y,(double)xf.z,(double)xf.w};
                const double wd[4] = {(double)wf.x,(double)wf.y,(double)wf.z,(double)wf.w};
                #pragma unroll
                for (int i=0;i<4;i++) {
                    #pragma unroll
                    for (int j=0;j<4;j++)
                        acc0[i][j] = fma(xd[i], wd[j], acc0[i][j]);
                }
            }
        }
        #pragma unroll
        for (int j=0;j<4;j++) {
            const double bj = (double)bb[head*64 + cg*4 + j];
            #pragma unroll
            for (int i=0;i<4;i++) {
                const double v  = acc0[i][j] + bj;
                const float  hi = (float)v;
                h_hi[(cg*4+j)*68 + rg*4 + i] = hi;
                h_lo[(cg*4+j)*68 + rg*4 + i] = __float2bfloat16((float)(v - (double)hi));
            }
        }
    }

    // ================= Phase 1: scaled logits + exp2 Z + top-8 =================
    int psel = 0;                 // pools: [fqk,fqk,fv,rqk,rqk,rv]
    if (head >= 2) psel = 1;
    if (head >= 3) psel = 2;
    if (head >= 5) psel = 3;
    const float* epool = emb + (size_t)psel * NPOOL * DSP;

    float zrow[4], tv[4][8];
    int   ti[4][8];
    #pragma unroll
    for (int i=0;i<4;i++) {
        zrow[i] = 0.f;
        #pragma unroll
        for (int s=0;s<8;s++) { tv[i][s] = -INFINITY; ti[i][s] = 0x7fffffff; }
    }

    const int erow = t >> 2;      // 0..63
    const int eq   = t & 3;
    const float4 zero4 = make_float4(0.f,0.f,0.f,0.f);

    for (int ch=0; ch<NCHUNKS; ++ch) {
        const float* esrc = epool + (size_t)(ch*CHUNK + erow)*DSP + eq*16;
        const float4 f0 = *(const float4*)(esrc);
        const float4 f1 = *(const float4*)(esrc + 4);
        const float4 f2 = *(const float4*)(esrc + 8);
        const float4 f3 = *(const float4*)(esrc + 12);
        // spread output zero-fill across chunks (stores issued after the loads)
        #pragma unroll
        for (int q=0;q<4;q++)
            *(float4*)(out + obase + (size_t)((ch*4+q)*256 + t)*4) = zero4;

        float ss = f0.x*f0.x + f0.y*f0.y + f0.z*f0.z + f0.w*f0.w
                 + f1.x*f1.x + f1.y*f1.y + f1.z*f1.z + f1.w*f1.w
                 + f2.x*f2.x + f2.y*f2.y + f2.z*f2.z + f2.w*f2.w
                 + f3.x*f3.x + f3.y*f3.y + f3.z*f3.z + f3.w*f3.w;
        ss += __shfl_xor(ss, 1, 64);
        ss += __shfl_xor(ss, 2, 64);
        const float inv = LOG2E_F / fmaxf(sqrtf(ss), 1e-12f);  // fold log2e into e
        __syncthreads();   // prev chunk's e reads done
        {
            const int k0 = eq*16;
            stage[(k0+ 0)*68 + erow] = f0.x*inv;
            stage[(k0+ 1)*68 + erow] = f0.y*inv;
            stage[(k0+ 2)*68 + erow] = f0.z*inv;
            stage[(k0+ 3)*68 + erow] = f0.w*inv;
            stage[(k0+ 4)*68 + erow] = f1.x*inv;
            stage[(k0+ 5)*68 + erow] = f1.y*inv;
            stage[(k0+ 6)*68 + erow] = f1.z*inv;
            stage[(k0+ 7)*68 + erow] = f1.w*inv;
            stage[(k0+ 8)*68 + erow] = f2.x*inv;
            stage[(k0+ 9)*68 + erow] = f2.y*inv;
            stage[(k0+10)*68 + erow] = f2.z*inv;
            stage[(k0+11)*68 + erow] = f2.w*inv;
            stage[(k0+12)*68 + erow] = f3.x*inv;
            stage[(k0+13)*68 + erow] = f3.y*inv;
            stage[(k0+14)*68 + erow] = f3.z*inv;
            stage[(k0+15)*68 + erow] = f3.w*inv;
        }
        __syncthreads();

        float acc[4][4];
        #pragma unroll
        for (int i=0;i<4;i++) {
            #pragma unroll
            for (int j=0;j<4;j++) acc[i][j] = 0.f;
        }
        #pragma unroll 4
        for (int k=0;k<DSP;k++) {
            const float4 hv = *(const float4*)&h_hi[k*68 + rg*4];
            const float4 ev = *(const float4*)&stage[k*68 + cg*4];
            const float ha[4] = {hv.x, hv.y, hv.z, hv.w};
            const float ea[4] = {ev.x, ev.y, ev.z, ev.w};
            #pragma unroll
            for (int i=0;i<4;i++) {
                #pragma unroll
                for (int j=0;j<4;j++)
                    acc[i][j] = fmaf(ha[i], ea[j], acc[i][j]);
            }
        }
        const int colbase = ch*CHUNK + cg*4;
        #pragma unroll
        for (int i=0;i<4;i++) {
            #pragma unroll
            for (int j=0;j<4;j++) {
                const float w = acc[i][j];
                const int   c = colbase + j;
                zrow[i] += exp2f(w - C2);
                if (bet_f(w, c, tv[i][7], ti[i][7])) {
                    tv[i][7] = w; ti[i][7] = c;
                    #pragma unroll
                    for (int s=7;s>0;--s) {
                        const bool sw = bet_f(tv[i][s],ti[i][s],tv[i][s-1],ti[i][s-1]);
                        const float a = tv[i][s]; const int b = ti[i][s];
                        tv[i][s]   = sw ? tv[i][s-1] : tv[i][s];
                        ti[i][s]   = sw ? ti[i][s-1] : ti[i][s];
                        tv[i][s-1] = sw ? a : tv[i][s-1];
                        ti[i][s-1] = sw ? b : ti[i][s-1];
                    }
                }
            }
        }
    }

    // ================= Phase 2: Z via shuffle; top-16 merge via LDS =================
    #pragma unroll
    for (int i=0;i<4;i++) {
        float zr = zrow[i];
        zr += __shfl_xor(zr, 1, 64);
        zr += __shfl_xor(zr, 2, 64);
        zr += __shfl_xor(zr, 4, 64);
        zr += __shfl_xor(zr, 8, 64);
        if (cg == 0) zbuf[rg*4 + i] = zr;
    }

    float* cand = stage;          // [64][66]
    float gv[KEEP]; int gi[KEEP];
    if (t < 64) {
        #pragma unroll
        for (int s=0;s<KEEP;s++) { gv[s] = -INFINITY; gi[s] = 0x7fffffff; }
    }
    for (int r=0;r<4;r++) {
        __syncthreads();   // round 0: also orders last e reads vs cand writes
        if ((cg>>2) == r) {
            #pragma unroll
            for (int i=0;i<4;i++) {
                #pragma unroll
                for (int s=0;s<8;s++) {
                    cand[(rg*4+i)*66 + (cg&3)*16 + s*2    ] = tv[i][s];
                    cand[(rg*4+i)*66 + (cg&3)*16 + s*2 + 1] = __int_as_float(ti[i][s]);
                }
            }
        }
        __syncthreads();
        if (t < 64) {
            for (int g=0; g<4; ++g) {
                #pragma unroll
                for (int s=0;s<8;s++) {
                    const float v  = cand[t*66 + g*16 + s*2];
                    const int   ix = __float_as_int(cand[t*66 + g*16 + s*2 + 1]);
                    if (bet_f(v, ix, gv[KEEP-1], gi[KEEP-1])) {
                        gv[KEEP-1] = v; gi[KEEP-1] = ix;
                        #pragma unroll
                        for (int s2=KEEP-1; s2>0; --s2) {
                            const bool sw = bet_f(gv[s2],gi[s2],gv[s2-1],gi[s2-1]);
                            const float a = gv[s2]; const int b = gi[s2];
                            gv[s2]   = sw ? gv[s2-1] : gv[s2];
                            gi[s2]   = sw ? gi[s2-1] : gi[s2];
                            gv[s2-1] = sw ? a : gv[s2-1];
                            gi[s2-1] = sw ? b : gi[s2-1];
                        }
                    }
                }
            }
        }
    }
    __syncthreads();

    // ================= Phase 3: fp64 rescore of top-16 =================
    double* rv   = (double*)stage;          // [64][17] doubles (8704 B)
    int*    ridx = (int*)(stage + 2176);    // [64][17] ints
    if (t < 64) {
        #pragma unroll
        for (int s=0;s<KEEP;s++) ridx[t*17 + s] = gi[s];
    }
    __syncthreads();
    {
        const int row = t >> 2, q = t & 3;  // 4 candidates per thread
        int ixs[4];
        const float* ep[4];
        #pragma unroll
        for (int s=0;s<4;s++) {
            ixs[s] = ridx[row*17 + q*4 + s];
            ep[s]  = epool + (size_t)ixs[s]*DSP;
        }
        double nn[4] = {0,0,0,0}, dd[4] = {0,0,0,0};
        for (int k4=0; k4<DSP; k4+=4) {
            double h4[4];
            #pragma unroll
            for (int u=0;u<4;u++)
                h4[u] = (double)h_hi[(k4+u)*68 + row]
                      + (double)__bfloat162float(h_lo[(k4+u)*68 + row]);
            #pragma unroll
            for (int s=0;s<4;s++) {
                const float4 evv = *(const float4*)(ep[s] + k4);
                const double e0 = (double)evv.x, e1 = (double)evv.y;
                const double e2 = (double)evv.z, e3 = (double)evv.w;
                nn[s] += e0*e0 + e1*e1 + e2*e2 + e3*e3;
                dd[s] += h4[0]*e0 + h4[1]*e1 + h4[2]*e2 + h4[3]*e3;
            }
        }
        #pragma unroll
        for (int s=0;s<4;s++)
            rv[row*17 + q*4 + s] = dd[s] / fmax(sqrt(nn[s]), 1e-12);
    }
    __syncthreads();   // also orders all zero-fill stores before the scatter

    // ================= Phase 4: fp64 top-8 + output =================
    if (t < 64) {
        const float Zg = zbuf[t];
        double bv[8]; int oi[8]; float ov[8];
        #pragma unroll
        for (int s=0;s<8;s++) { bv[s] = -INFINITY; oi[s] = 0x7fffffff; }
        for (int s=0;s<KEEP;s++) {
            const double v  = rv[t*17 + s];
            const int    ix = ridx[t*17 + s];
            if (bet_d(v, ix, bv[7], oi[7])) {
                bv[7] = v; oi[7] = ix;
                #pragma unroll
                for (int s2=7; s2>0; --s2) {
                    const bool sw = bet_d(bv[s2],oi[s2],bv[s2-1],oi[s2-1]);
                    const double a = bv[s2]; const int b = oi[s2];
                    bv[s2]   = sw ? bv[s2-1] : bv[s2];
                    oi[s2]   = sw ? oi[s2-1] : oi[s2];
                    bv[s2-1] = sw ? a : bv[s2-1];
                    oi[s2-1] = sw ? b : oi[s2-1];
                }
            }
        }
        float denom = 1e-8f * Zg;
        #pragma unroll
        for (int s=0;s<8;s++) {
            ov[s] = exp2f((float)(bv[s]*LOG2E_D) - C2);
            denom += ov[s];
        }
        const float rd = 1.0f / denom;
        float* orow = out + obase + (size_t)t*NPOOL;
        #pragma unroll
        for (int s=0;s<8;s++) orow[oi[s]] = ov[s]*rd;
    }
}

extern "C" void kernel_launch(void* const* d_in, const int* in_sizes, int n_in,
                              void* d_out, int out_size, void* d_ws, size_t ws_size,
                              hipStream_t stream) {
    (void)in_sizes; (void)n_in; (void)d_ws; (void)ws_size; (void)out_size;
    const float* x   = (const float*)d_in[0];
    const float* Wm  = (const float*)d_in[1];
    const float* bb  = (const float*)d_in[2];
    const float* emb = (const float*)d_in[3];
    dim3 grid(NROWS / TILE_M, HEADS);
    router_all<<<grid, dim3(256), 0, stream>>>(x, Wm, bb, emb, (float*)d_out);
}